// Round 12
// baseline (42.114 us; speedup 1.0000x reference)
//
#include <hip/hip_runtime.h>
#include <hip/hip_bf16.h>
#include <cstddef>

namespace {

constexpr int NB    = 8;
constexpr int LQn   = 2048;
constexpr int DM    = 256;
constexpr int S_TOT = 3840;   // 2048+1024+512+256
constexpr int BK    = 32;

typedef __attribute__((ext_vector_type(8))) short  short8;
typedef __attribute__((ext_vector_type(4))) float  f32x4;
typedef __attribute__((ext_vector_type(8))) _Float16 half8;
typedef __attribute__((ext_vector_type(4))) _Float16 half4;
typedef __attribute__((ext_vector_type(2))) _Float16 half2v;

// pack 4+4 f32 -> 8 bf16 via native v_cvt_pk_bf16_f32
union BF8 { __hip_bfloat162 h2[4]; short8 s8; };
__device__ inline short8 cvt8(const f32x4 a, const f32x4 b) {
  BF8 r;
  r.h2[0] = __float22bfloat162_rn(make_float2(a[0], a[1]));
  r.h2[1] = __float22bfloat162_rn(make_float2(a[2], a[3]));
  r.h2[2] = __float22bfloat162_rn(make_float2(b[0], b[1]));
  r.h2[3] = __float22bfloat162_rn(make_float2(b[2], b[3]));
  return r.s8;
}

// ---------------------------------------------------------------------------
// Merged bf16-MFMA GEMM, R12: tile 128 x 256 (ALL output columns in one
// block) so the A panel is read from HBM exactly ONCE. R11 and earlier used
// 128x128 tiles whose c0/c1 partners each fetched the full A panel: 96 MB of
// A traffic (measured G ~= 23 us ~= 120 MB / 6.3 TB/s). New traffic: 48 MB A
// + ~2 MB W (L2-resident) + 24 MB writes ~= 74 MB -> ~12 us floor.
// 512 threads = 8 waves (2m x 4n), each wave 64x64 out; BK=32 keeps
// VGPR <= 128 (launch_bounds(512,4) -> 2 blocks/CU; 368 blocks all-resident).
// LDS k-major: As[kg][128 rows][8 bf16], Bs[kg][256][8] -> fragment reads
// (16 lanes x consecutive rows at one kg) are contiguous/conflict-free, no
// XOR swizzle needed. Staging ds_writes take a 4-way bank conflict on 3
// insts/thread/k-step (accepted, ~free per m136 scale).
// Grid 368, XCD-aligned (id%8 == batch == XCD), matching the sampler.
// W JIT-staged (L2 hits); A one-k-step-ahead reg prefetch (8 VGPR); raw
// s_barrier + lgkmcnt(0) only -> A's vmcnt outstanding across MFMA phase.
// Epilogue: two 128-col halves via 34 KB LDS tile; value stored HEAD-MAJOR
// (N, M, 3840, 32) for the sampler; full 128 B line writes per wave.
// ---------------------------------------------------------------------------
union SMem {
  struct { short A[4 * 128 * 8]; short B[4 * 256 * 8]; } ab;  // 8 + 16 KB
  _Float16 c[128 * 136];                                       // 34 KB epi
};

__global__ __launch_bounds__(512, 4) void gemm_bf16_k(
    const float* __restrict__ A_val, const float* __restrict__ A_prj,
    const float* __restrict__ W_val, const float* __restrict__ b_val,
    const float* __restrict__ W_off, const float* __restrict__ b_off,
    const float* __restrict__ W_att, const float* __restrict__ b_att,
    _Float16* __restrict__ out_val, _Float16* __restrict__ out_prj)
{
  __shared__ SMem sm;
  char* As = reinterpret_cast<char*>(sm.ab.A);
  char* Bs = reinterpret_cast<char*>(sm.ab.B);

  const int tid  = threadIdx.x;
  const int lane = tid & 63;
  const int wid  = tid >> 6;     // 0..7
  const int wm   = wid >> 2;     // 0..1
  const int wn   = wid & 3;      // 0..3

  const int id = blockIdx.x;
  const float* A;
  bool isv;
  int r0, vbatch = 0, vtrow0 = 0;
  if (id < 240) {
    const int x = id & 7;        // XCD == batch
    const int s = id >> 3;       // 0..29
    A = A_val; r0 = (x * 30 + s) * 128;
    isv = true; vbatch = x; vtrow0 = s * 128;
  } else {
    const int j = id - 240;
    const int x = j & 7;
    const int s = j >> 3;        // 0..15
    A = A_prj; r0 = (x * 16 + s) * 128;
    isv = false;
  }

  // bias for this lane's 4 N-fragments (global col = wn*64 + ni*16 + rl)
  float bv[4];
  #pragma unroll
  for (int ni = 0; ni < 4; ++ni) {
    const int col = wn * 64 + ni * 16 + (lane & 15);
    bv[ni] = isv ? b_val[col]
                 : (col < 128 ? b_off[col] : b_att[col - 128]);
  }

  // staging assignment: kg-fast in tid for global coalescing
  const int arow = tid >> 2;     // 0..127
  const int akg  = tid & 3;      // 0..3

  // W row pointers (2 chunks/thread: rows arow and arow+128)
  const float* wrow0;
  const float* wrow1;
  if (isv) {
    wrow0 = W_val + (size_t)arow * DM;
    wrow1 = W_val + (size_t)(arow + 128) * DM;
  } else {
    wrow0 = W_off + (size_t)arow * DM;
    wrow1 = W_att + (size_t)arow * DM;   // rows 128..255 -> W_att[row-128]
  }

  f32x4 pa0, pa1;                // A prefetch (8 VGPR)
  auto load_A = [&](int k0) {
    const float* p = &A[(size_t)(r0 + arow) * DM + k0 + akg * 8];
    pa0 = *reinterpret_cast<const f32x4*>(p);
    pa1 = *reinterpret_cast<const f32x4*>(p + 4);
  };
  load_A(0);

  f32x4 acc[4][4] = {};

  for (int k = 0; k < 8; ++k) {
    const int k0 = k * BK;
    // ---- phase 1a: W JIT staging (L2-hit loads, 2 chunks) ----
    {
      const float* p0 = wrow0 + k0 + akg * 8;
      const f32x4 w00 = *reinterpret_cast<const f32x4*>(p0);
      const f32x4 w01 = *reinterpret_cast<const f32x4*>(p0 + 4);
      const short8 sw0 = cvt8(w00, w01);
      *reinterpret_cast<short8*>(Bs + akg * 4096 + arow * 16) = sw0;
      const float* p1 = wrow1 + k0 + akg * 8;
      const f32x4 w10 = *reinterpret_cast<const f32x4*>(p1);
      const f32x4 w11 = *reinterpret_cast<const f32x4*>(p1 + 4);
      const short8 sw1 = cvt8(w10, w11);
      *reinterpret_cast<short8*>(Bs + akg * 4096 + (arow + 128) * 16) = sw1;
    }
    // ---- phase 1b: A convert + LDS write (data-dep wait on pa) ----
    {
      const short8 sa = cvt8(pa0, pa1);
      *reinterpret_cast<short8*>(As + akg * 2048 + arow * 16) = sa;
    }
    // issue next A tile's HBM loads; stay in flight across barrier + MFMA
    if (k < 7) load_A(k0 + BK);

    asm volatile("s_waitcnt lgkmcnt(0)" ::: "memory");
    __builtin_amdgcn_sched_barrier(0);
    __builtin_amdgcn_s_barrier();
    __builtin_amdgcn_sched_barrier(0);

    // ---- phase 2: fragments + MFMA (k-major LDS, conflict-free) ----
    {
      const int kgl = lane >> 4;     // 0..3
      const int rl  = lane & 15;
      short8 af[4], bfr[4];
      #pragma unroll
      for (int mi = 0; mi < 4; ++mi)
        af[mi] = *reinterpret_cast<const short8*>(
            As + kgl * 2048 + (wm * 64 + mi * 16 + rl) * 16);
      #pragma unroll
      for (int ni = 0; ni < 4; ++ni)
        bfr[ni] = *reinterpret_cast<const short8*>(
            Bs + kgl * 4096 + (wn * 64 + ni * 16 + rl) * 16);
      #pragma unroll
      for (int mi = 0; mi < 4; ++mi)
        #pragma unroll
        for (int ni = 0; ni < 4; ++ni)
          acc[mi][ni] = __builtin_amdgcn_mfma_f32_16x16x32_bf16(
              af[mi], bfr[ni], acc[mi][ni], 0, 0, 0);
    }

    asm volatile("s_waitcnt lgkmcnt(0)" ::: "memory");
    __builtin_amdgcn_sched_barrier(0);
    __builtin_amdgcn_s_barrier();
    __builtin_amdgcn_sched_barrier(0);
  }

  // ---- epilogue: two 128-col halves through the 34 KB LDS tile ----
  #pragma unroll
  for (int hh = 0; hh < 2; ++hh) {
    if ((wn >> 1) == hh) {
      #pragma unroll
      for (int mi = 0; mi < 4; ++mi) {
        const int row = wm * 64 + mi * 16 + (lane >> 4) * 4;
        #pragma unroll
        for (int ni = 0; ni < 4; ++ni) {
          const int coll = (wn & 1) * 64 + ni * 16 + (lane & 15);
          #pragma unroll
          for (int j = 0; j < 4; ++j)
            sm.c[(row + j) * 136 + coll] = (_Float16)(acc[mi][ni][j] + bv[ni]);
        }
      }
    }
    __syncthreads();
    #pragma unroll
    for (int i = 0; i < 4; ++i) {
      const int ch  = tid + i * 512;   // 0..2047
      const int row = ch >> 4;         // 0..127
      const int cc  = ch & 15;         // 8-f16 chunk within the 128-col half
      const half8 v = *reinterpret_cast<const half8*>(&sm.c[row * 136 + cc * 8]);
      if (isv) {
        const int h = hh * 4 + (cc >> 2);   // global head 0..7
        _Float16* dst = out_val +
            ((size_t)(vbatch * 8 + h) * S_TOT + vtrow0 + row) * 32 + (cc & 3) * 8;
        *reinterpret_cast<half8*>(dst) = v;
      } else {
        *reinterpret_cast<half8*>(
            &out_prj[(size_t)(r0 + row) * DM + hh * 128 + cc * 8]) = v;
      }
    }
    __syncthreads();
  }
}

// ---------------------------------------------------------------------------
// Sampler v6 (unchanged R11): head-major value (N, M, 3840, 32). Block = 512
// threads = 8 queries, XCD-swizzled grid (n = blockIdx&7 == XCD).
// Prep (t<256): (q,m,sub-level) -> 4-lane shfl softmax -> tap table in LDS.
// Gather: thread (q=wave, m, dg, th) does 8 taps, batch-issued depth-2
// pipeline; shfl_xor(4) partner merge. Measured S ~= 16.7 us ~= the L2
// request-rate floor (262K wave-gather-insts x ~1 cy / 8 XCDs) -- at floor.
// ---------------------------------------------------------------------------
__global__ __launch_bounds__(512) void sample_k(
    const _Float16* __restrict__ proj,    // (N*LQ, 256) f16
    const float* __restrict__ refp,       // (N, LQ, 4)
    const _Float16* __restrict__ value,   // (N, 8, 3840, 32) f16 head-major
    float* __restrict__ out)              // (N, LQ, 256)
{
  __shared__ uint4 tap_s[8][136];   // [q][m*17 + tap], 17.4 KB

  const int d     = blockIdx.x;
  const int n     = d & 7;
  const int chunk = d >> 3;
  const int row0q = n * LQn + chunk * 8;
  const int t     = threadIdx.x;

  const int lens[4]   = {2048, 1024, 512, 256};
  const int starts[4] = {0, 2048, 3072, 3584};

  // ---- prep: softmax + tap table ----
  if (t < 256) {
    const int q   = t >> 5;
    const int m   = (t >> 2) & 7;
    const int sub = t & 3;              // == level l
    const int j0  = m * 16 + sub * 4;
    const size_t prow = (size_t)(row0q + q) * DM;

    const half4 offv = *reinterpret_cast<const half4*>(&proj[prow + j0]);
    const half4 lgv  = *reinterpret_cast<const half4*>(&proj[prow + 128 + j0]);
    float lg[4], off[4];
    #pragma unroll
    for (int i = 0; i < 4; ++i) { lg[i] = (float)lgv[i]; off[i] = (float)offv[i]; }

    float mx = fmaxf(fmaxf(lg[0], lg[1]), fmaxf(lg[2], lg[3]));
    mx = fmaxf(mx, __shfl_xor(mx, 1));
    mx = fmaxf(mx, __shfl_xor(mx, 2));
    float e[4], s = 0.f;
    #pragma unroll
    for (int i = 0; i < 4; ++i) { e[i] = __expf(lg[i] - mx); s += e[i]; }
    s += __shfl_xor(s, 1);
    s += __shfl_xor(s, 2);
    const float inv = 1.f / s;

    const int   T  = lens[sub];
    const int   st = starts[sub];
    const float fT = (float)T;
    const float rf = refp[(size_t)(row0q + q) * 4 + sub];
    #pragma unroll
    for (int i = 0; i < 4; ++i) {
      const float a  = e[i] * inv;
      const float ix = fmaf(rf, fT, off[i] - 0.5f);
      const float fl = floorf(ix);
      const float w1 = ix - fl;
      const int   i0 = (int)fl;
      const int   i1 = i0 + 1;
      const float wa = (i0 >= 0 && i0 < T) ? a * (1.f - w1) : 0.f;
      const float wb = (i1 >= 0 && i1 < T) ? a * w1 : 0.f;
      const int   r0b = (st + min(max(i0, 0), T - 1)) * 64;   // 64 B rows
      const int   r1b = (st + min(max(i1, 0), T - 1)) * 64;
      union { half2v h; unsigned u; } pw;
      pw.h.x = (_Float16)wa; pw.h.y = (_Float16)wb;
      uint4 ent; ent.x = pw.u; ent.y = (unsigned)r0b; ent.z = (unsigned)r1b; ent.w = 0u;
      tap_s[q][m * 17 + sub * 4 + i] = ent;
    }
  }
  __syncthreads();

  // ---- gather (batch-issued, depth-2 pipelined, head-major slab) ----
  const int q  = t >> 6;          // wave id = query
  const int l  = t & 63;
  const int m  = l >> 3;
  const int dg = l & 3;
  const int th = (l >> 2) & 1;    // tap-half
  const char* vb = reinterpret_cast<const char*>(value) +
                   (size_t)(n * 8 + m) * S_TOT * 64 + dg * 16;

  uint4 e[8];
  #pragma unroll
  for (int i = 0; i < 8; ++i) e[i] = tap_s[q][m * 17 + th * 8 + i];

  float acc[8] = {};
  half8 v0[4], v1[4];
  #pragma unroll
  for (int i = 0; i < 4; ++i) {
    v0[i] = *reinterpret_cast<const half8*>(vb + e[i].y);
    v1[i] = *reinterpret_cast<const half8*>(vb + e[i].z);
  }
  #pragma unroll
  for (int i = 0; i < 8; ++i) {
    const int s = i & 3;
    union { unsigned u; half2v h; } pw; pw.u = e[i].x;
    const float wa = (float)pw.h.x;
    const float wb = (float)pw.h.y;
    const half8 a0 = v0[s];
    const half8 a1 = v1[s];
    if (i < 4) {   // prefetch second half while consuming first
      v0[s] = *reinterpret_cast<const half8*>(vb + e[i + 4].y);
      v1[s] = *reinterpret_cast<const half8*>(vb + e[i + 4].z);
    }
    #pragma unroll
    for (int j = 0; j < 8; ++j)
      acc[j] = fmaf(wa, (float)a0[j], fmaf(wb, (float)a1[j], acc[j]));
  }

  #pragma unroll
  for (int j = 0; j < 8; ++j) acc[j] += __shfl_xor(acc[j], 4);

  if (th == 0) {
    float* op = &out[(size_t)(row0q + q) * DM + m * 32 + dg * 8];
    f32x4 o0 = {acc[0], acc[1], acc[2], acc[3]};
    f32x4 o1 = {acc[4], acc[5], acc[6], acc[7]};
    *reinterpret_cast<f32x4*>(op)     = o0;
    *reinterpret_cast<f32x4*>(op + 4) = o1;
  }
}

}  // namespace

extern "C" void kernel_launch(void* const* d_in, const int* in_sizes, int n_in,
                              void* d_out, int out_size, void* d_ws, size_t ws_size,
                              hipStream_t stream) {
  const float* query  = (const float*)d_in[0];   // (8,2048,256)
  const float* refp   = (const float*)d_in[1];   // (8,2048,4,1)
  const float* inflat = (const float*)d_in[2];   // (8,3840,256)
  const float* W_val  = (const float*)d_in[5];   // (256,256)
  const float* b_val  = (const float*)d_in[6];   // (256,)
  const float* W_off  = (const float*)d_in[7];   // (128,256)
  const float* b_off  = (const float*)d_in[8];   // (128,)
  const float* W_attn = (const float*)d_in[9];   // (128,256)
  const float* b_attn = (const float*)d_in[10];  // (128,)
  float* out = (float*)d_out;

  // workspace: value f16 head-major (8*8*3840*32 = 15.73 MB) | proj f16 (8.4 MB)
  _Float16* value_h = (_Float16*)d_ws;
  _Float16* proj_h  = (_Float16*)((char*)d_ws +
                      (size_t)NB * S_TOT * DM * sizeof(_Float16));

  // merged GEMM: 240 value blocks + 128 proj blocks, 256-wide tiles
  // (A read once), XCD-aligned
  gemm_bf16_k<<<dim3(368), dim3(512), 0, stream>>>(
      inflat, query, W_val, b_val, W_off, b_off, W_attn, b_attn,
      value_h, proj_h);

  // softmax + bilinear sampling + head-mix (XCD-aligned to the GEMM's L2)
  sample_k<<<dim3(NB * LQn / 8), dim3(512), 0, stream>>>(
      proj_h, refp, value_h, out);
}